// Round 10
// baseline (449.153 us; speedup 1.0000x reference)
//
#include <hip/hip_runtime.h>
#include <math.h>

typedef __attribute__((ext_vector_type(8))) short bf16x8;
typedef __attribute__((ext_vector_type(4))) float f32x4;
typedef __attribute__((ext_vector_type(4))) unsigned short u16x4;

#define NB 64
#define NS 4096
#define NH 512
#define NE 1024
#define APITCH 80  // 64B bf16 K-row + 16B pad (mult of 16): conflict-free b128 reads

__device__ __forceinline__ unsigned short f2bf(float f) {
  unsigned int u = __float_as_uint(f);
  u += 0x7fffu + ((u >> 16) & 1u);
  return (unsigned short)(u >> 16);
}

__device__ __forceinline__ float fast_tanh(float x) {
  float e = __expf(2.0f * x);
  return 1.0f - 2.0f * __builtin_amdgcn_rcpf(e + 1.0f);
}

// ---- pack W (f32 [512][1024]) into MFMA B-fragment order, bf16 ----
// chunk c = ((w*32 + kb)*4 + ni); lane l's 16B = W[w*64+ni*16+(l&15)][kb*32+(l>>4)*8 .. +7]
__global__ __launch_bounds__(256) void prep_b_kernel(const float* __restrict__ W,
                                                     unsigned short* __restrict__ Bp) {
  const int t = blockIdx.x * 256 + threadIdx.x;  // 0..65535
  const int lane = t & 63;
  const int ni = (t >> 6) & 3;
  const int kb = (t >> 8) & 31;
  const int w = t >> 13;
  const int col = w * 64 + ni * 16 + (lane & 15);
  const int k0 = kb * 32 + (lane >> 4) * 8;
  const float* src = W + col * NE + k0;
  float4 a = *(const float4*)src;
  float4 b = *(const float4*)(src + 4);
  union { bf16x8 v; unsigned short u[8]; } p;
  p.u[0] = f2bf(a.x); p.u[1] = f2bf(a.y); p.u[2] = f2bf(a.z); p.u[3] = f2bf(a.w);
  p.u[4] = f2bf(b.x); p.u[5] = f2bf(b.y); p.u[6] = f2bf(b.z); p.u[7] = f2bf(b.w);
  *(bf16x8*)(Bp + (long long)t * 8) = p.v;
}

// ---- prep: dec[b,h] = decoder_output[b,:] . W_s_w[h,:] + W_s_b[h] + W_h_b[h] ----
__global__ __launch_bounds__(512) void prep_dec_kernel(const float* __restrict__ dec,
                                                       const float* __restrict__ Wsw,
                                                       const float* __restrict__ Wsb,
                                                       const float* __restrict__ Whb,
                                                       float* __restrict__ decb) {
  int b = blockIdx.x;
  int h = threadIdx.x;
  const float4* dr = (const float4*)(dec + b * NH);
  const float4* wr = (const float4*)(Wsw + h * NH);
  float sum = Wsb[h] + Whb[h];
#pragma unroll 8
  for (int i = 0; i < NH / 4; ++i) {
    float4 a = dr[i], w = wr[i];
    sum += a.x * w.x + a.y * w.y + a.z * w.z + a.w * w.w;
  }
  decb[b * NH + h] = sum;
}

// ---- main: enc-proj GEMM (bf16 MFMA) + bias + tanh + v-dot -> scores ----
// R10 RESTRUCTURE (m201 design point): BM=128, BN=512, BK=32, 512 thr / 8 waves,
// __launch_bounds__(512,2) -> 256-reg budget, 1 block/CU (2 waves/SIMD).
// acc[8][4]=128 regs. Deep prefetch now FITS: B ping-pong issued at step top
// (full step to land), af(t+1) read-ahead interleaved with MFMA groups,
// A(t+2) f32 load top / cvt+write mid via 4 rotating LDS buffers (no races).
__global__ __launch_bounds__(512, 2) void fused_main(const float* __restrict__ enc,
                                                     const unsigned short* __restrict__ Bp,
                                                     const float* __restrict__ decb,
                                                     const float* __restrict__ vw,
                                                     float* __restrict__ scores) {
  __shared__ __align__(16) char As[4][128 * APITCH];  // 4 x 10KB rotating bf16 tiles
  __shared__ float ssc[128];

  const int tid = threadIdx.x;
  const int lane = tid & 63;
  const int wave = tid >> 6;
  const int r15 = lane & 15;
  const int c4 = lane >> 4;
  const long long m0 = (long long)blockIdx.x * 128;

  if (tid < 128) ssc[tid] = 0.0f;

  // A staging: thread t -> row t>>2 (0..127), chunk t&3 (8 f32 = 32B)
  const int arow = tid >> 2;
  const int achk = tid & 3;
  const float* aload = enc + (m0 + arow) * NE + achk * 8;
  const int awr = arow * APITCH + achk * 16;  // bf16 bytes, 16B-aligned
  const int rdb = r15 * APITCH + c4 * 16;     // frag read base (+ mi*16*APITCH)

  const unsigned short* const bb = Bp + (long long)wave * 32 * 2048 + lane * 8;

  f32x4 acc[8][4];
#pragma unroll
  for (int mi = 0; mi < 8; ++mi)
#pragma unroll
    for (int ni = 0; ni < 4; ++ni) {
      f32x4 z = {0.f, 0.f, 0.f, 0.f};
      acc[mi][ni] = z;
    }

  // prologue: B(0)->bEv; A(0)->buf0, A(1)->buf1 (direct cvt); A(2)->regs; af(0) pre-read
  bf16x8 bEv[4], bOd[4];
#pragma unroll
  for (int ni = 0; ni < 4; ++ni) bEv[ni] = *(const bf16x8*)(bb + ni * 512);
#pragma unroll
  for (int s = 0; s < 2; ++s) {
    float4 p0 = *(const float4*)(aload + s * 32);
    float4 p1 = *(const float4*)(aload + s * 32 + 4);
    uint4 wv;
    asm("v_cvt_pk_bf16_f32 %0, %1, %2" : "=v"(wv.x) : "v"(p0.x), "v"(p0.y));
    asm("v_cvt_pk_bf16_f32 %0, %1, %2" : "=v"(wv.y) : "v"(p0.z), "v"(p0.w));
    asm("v_cvt_pk_bf16_f32 %0, %1, %2" : "=v"(wv.z) : "v"(p1.x), "v"(p1.y));
    asm("v_cvt_pk_bf16_f32 %0, %1, %2" : "=v"(wv.w) : "v"(p1.z), "v"(p1.w));
    *(uint4*)(&As[s][0] + awr) = wv;
  }
  float4 ap0 = *(const float4*)(aload + 64);      // A(2) f32
  float4 ap1 = *(const float4*)(aload + 64 + 4);
  asm volatile("s_waitcnt lgkmcnt(0)" ::: "memory");
  __builtin_amdgcn_s_barrier();

  bf16x8 af[8];
#pragma unroll
  for (int mi = 0; mi < 8; ++mi)
    af[mi] = *(const bf16x8*)(&As[0][0] + mi * 16 * APITCH + rdb);

#pragma unroll
  for (int t = 0; t < 32; ++t) {
    // ---- step top: B(t+1) into opposite parity set; A(t+2) f32 loads ----
    if (t < 31) {
      const bf16x8* bp = (const bf16x8*)(bb + (t + 1) * 2048);
      if (t & 1) {
#pragma unroll
        for (int ni = 0; ni < 4; ++ni) bEv[ni] = bp[ni * 64];
      } else {
#pragma unroll
        for (int ni = 0; ni < 4; ++ni) bOd[ni] = bp[ni * 64];
      }
    }
    if (t < 30) {
      ap0 = *(const float4*)(aload + (t + 2) * 32);
      ap1 = *(const float4*)(aload + (t + 2) * 32 + 4);
    }
    // ---- MFMA cluster: 8 m-groups x 4 ni; af(t+1) read-ahead after each group ----
    const char* Abn = &As[(t + 1) & 3][0];
    __builtin_amdgcn_s_setprio(1);
#pragma unroll
    for (int mi = 0; mi < 8; ++mi) {
#pragma unroll
      for (int ni = 0; ni < 4; ++ni)
        acc[mi][ni] = __builtin_amdgcn_mfma_f32_16x16x32_bf16(
            af[mi], (t & 1) ? bOd[ni] : bEv[ni], acc[mi][ni], 0, 0, 0);
      if (t < 31) af[mi] = *(const bf16x8*)(Abn + mi * 16 * APITCH + rdb);
    }
    __builtin_amdgcn_s_setprio(0);
    // ---- A(t+2) cvt + write into buffer (t+2)&3 (read next step, race-free) ----
    if (t < 30) {
      uint4 wv;
      asm("v_cvt_pk_bf16_f32 %0, %1, %2" : "=v"(wv.x) : "v"(ap0.x), "v"(ap0.y));
      asm("v_cvt_pk_bf16_f32 %0, %1, %2" : "=v"(wv.y) : "v"(ap0.z), "v"(ap0.w));
      asm("v_cvt_pk_bf16_f32 %0, %1, %2" : "=v"(wv.z) : "v"(ap1.x), "v"(ap1.y));
      asm("v_cvt_pk_bf16_f32 %0, %1, %2" : "=v"(wv.w) : "v"(ap1.z), "v"(ap1.w));
      *(uint4*)(&As[(t + 2) & 3][0] + awr) = wv;
    }
    asm volatile("s_waitcnt lgkmcnt(0)" ::: "memory");
    __builtin_amdgcn_sched_barrier(0);
    __builtin_amdgcn_s_barrier();
  }

  // epilogue: x = tanh(acc + dec[b,h]); score += v[h]*x
  // C/D layout: col = lane&15 (n), row = (lane>>4)*4 + j (m)
  const int bidx = (int)(m0 >> 12);
  const float* decrow = decb + bidx * NH;
  float part[8][4];
#pragma unroll
  for (int mi = 0; mi < 8; ++mi)
#pragma unroll
    for (int j = 0; j < 4; ++j) part[mi][j] = 0.f;

#pragma unroll
  for (int ni = 0; ni < 4; ++ni) {
    int col = (wave << 6) + ni * 16 + r15;
    float vc = vw[col];
    float dc = decrow[col];
#pragma unroll
    for (int mi = 0; mi < 8; ++mi)
#pragma unroll
      for (int j = 0; j < 4; ++j)
        part[mi][j] += vc * fast_tanh(acc[mi][ni][j] + dc);
  }
#pragma unroll
  for (int off = 1; off < 16; off <<= 1)
#pragma unroll
    for (int mi = 0; mi < 8; ++mi)
#pragma unroll
      for (int j = 0; j < 4; ++j)
        part[mi][j] += __shfl_xor(part[mi][j], off, 64);

  if (r15 == 0) {
#pragma unroll
    for (int mi = 0; mi < 8; ++mi)
#pragma unroll
      for (int j = 0; j < 4; ++j)
        atomicAdd(&ssc[mi * 16 + c4 * 4 + j], part[mi][j]);
  }
  __syncthreads();
  if (tid < 128) scores[m0 + tid] = ssc[tid];
}

// ---- masked softmax over S per batch row ----
__global__ __launch_bounds__(1024) void softmax_kernel(const float* __restrict__ scores,
                                                       const int* __restrict__ mask,
                                                       float* __restrict__ out) {
  __shared__ float rmax[16];
  __shared__ float rsum[16];
  const int b = blockIdx.x;
  const int t = threadIdx.x;
  const int wid = t >> 6;
  const int ln = t & 63;
  const int base = b * NS;

  float s[4];
  int mk[4];
  float mx = -INFINITY;
#pragma unroll
  for (int i = 0; i < 4; ++i) {
    int idx = t + i * 1024;
    s[i] = scores[base + idx];
    mk[i] = mask[base + idx];
    if (mk[i]) mx = fmaxf(mx, s[i]);
  }
#pragma unroll
  for (int off = 1; off < 64; off <<= 1) mx = fmaxf(mx, __shfl_xor(mx, off, 64));
  if (ln == 0) rmax[wid] = mx;
  __syncthreads();
  float m2 = -INFINITY;
#pragma unroll
  for (int i = 0; i < 16; ++i) m2 = fmaxf(m2, rmax[i]);

  float e[4];
  float sum = 0.f;
#pragma unroll
  for (int i = 0; i < 4; ++i) {
    e[i] = mk[i] ? expf(s[i] - m2) : 0.f;
    sum += e[i];
  }
#pragma unroll
  for (int off = 1; off < 64; off <<= 1) sum += __shfl_xor(sum, off, 64);
  if (ln == 0) rsum[wid] = sum;
  __syncthreads();
  float tot = 0.f;
#pragma unroll
  for (int i = 0; i < 16; ++i) tot += rsum[i];
  float inv = 1.0f / tot;
#pragma unroll
  for (int i = 0; i < 4; ++i) {
    int idx = t + i * 1024;
    out[base + idx] = e[i] * inv;
  }
}

extern "C" void kernel_launch(void* const* d_in, const int* in_sizes, int n_in,
                              void* d_out, int out_size, void* d_ws, size_t ws_size,
                              hipStream_t stream) {
  const float* dec = (const float*)d_in[0];   // [64,512]
  const float* enc = (const float*)d_in[1];   // [64,4096,1024]
  const int* mask = (const int*)d_in[2];      // [64,4096]
  const float* Whw = (const float*)d_in[3];   // [512,1024]
  const float* Whb = (const float*)d_in[4];   // [512]
  const float* Wsw = (const float*)d_in[5];   // [512,512]
  const float* Wsb = (const float*)d_in[6];   // [512]
  const float* vw = (const float*)d_in[7];    // [1,512]
  float* out = (float*)d_out;                 // [64,4096]

  unsigned short* Bp = (unsigned short*)d_ws;                         // 1 MB packed W
  float* decb = (float*)((char*)d_ws + (1 << 20));                    // 128 KB
  float* scoresb = (float*)((char*)d_ws + (1 << 20) + (128 << 10));   // 1 MB

  prep_b_kernel<<<dim3(256), dim3(256), 0, stream>>>(Whw, Bp);
  prep_dec_kernel<<<dim3(64), dim3(512), 0, stream>>>(dec, Wsw, Wsb, Whb, decb);
  fused_main<<<dim3(2048), dim3(512), 0, stream>>>(enc, Bp, decb, vw, scoresb);
  softmax_kernel<<<dim3(64), dim3(1024), 0, stream>>>(scoresb, mask, out);
}

// Round 11
// 400.310 us; speedup vs baseline: 1.1220x; 1.1220x over previous
//
#include <hip/hip_runtime.h>
#include <math.h>

typedef __attribute__((ext_vector_type(8))) short bf16x8;
typedef __attribute__((ext_vector_type(4))) float f32x4;
typedef __attribute__((ext_vector_type(4))) unsigned short u16x4;

#define NB 64
#define NS 4096
#define NH 512
#define NE 1024
#define APITCH 80  // 64B bf16 K-row + 16B pad: conflict-free-enough (<=2-way) b128 reads

__device__ __forceinline__ unsigned short f2bf(float f) {
  unsigned int u = __float_as_uint(f);
  u += 0x7fffu + ((u >> 16) & 1u);
  return (unsigned short)(u >> 16);
}

__device__ __forceinline__ float fast_tanh(float x) {
  float e = __expf(2.0f * x);
  return 1.0f - 2.0f * __builtin_amdgcn_rcpf(e + 1.0f);
}

// ---- pack W (f32 [512][1024]) into MFMA B-fragment order, bf16 ----
// chunk c = ((g*32 + kb)*4 + ni); lane l's 16B = W[g*64+ni*16+(l&15)][kb*32+(l>>4)*8 .. +7]
// (g = N-group 0..7; in the main kernel g = wave&7 so wave pairs share chunks)
__global__ __launch_bounds__(256) void prep_b_kernel(const float* __restrict__ W,
                                                     unsigned short* __restrict__ Bp) {
  const int t = blockIdx.x * 256 + threadIdx.x;  // 0..65535
  const int lane = t & 63;
  const int ni = (t >> 6) & 3;
  const int kb = (t >> 8) & 31;
  const int g = t >> 13;
  const int col = g * 64 + ni * 16 + (lane & 15);
  const int k0 = kb * 32 + (lane >> 4) * 8;
  const float* src = W + col * NE + k0;
  float4 a = *(const float4*)src;
  float4 b = *(const float4*)(src + 4);
  union { bf16x8 v; unsigned short u[8]; } p;
  p.u[0] = f2bf(a.x); p.u[1] = f2bf(a.y); p.u[2] = f2bf(a.z); p.u[3] = f2bf(a.w);
  p.u[4] = f2bf(b.x); p.u[5] = f2bf(b.y); p.u[6] = f2bf(b.z); p.u[7] = f2bf(b.w);
  *(bf16x8*)(Bp + (long long)t * 8) = p.v;
}

// ---- prep: dec[b,h] = decoder_output[b,:] . W_s_w[h,:] + W_s_b[h] + W_h_b[h] ----
__global__ __launch_bounds__(512) void prep_dec_kernel(const float* __restrict__ dec,
                                                       const float* __restrict__ Wsw,
                                                       const float* __restrict__ Wsb,
                                                       const float* __restrict__ Whb,
                                                       float* __restrict__ decb) {
  int b = blockIdx.x;
  int h = threadIdx.x;
  const float4* dr = (const float4*)(dec + b * NH);
  const float4* wr = (const float4*)(Wsw + h * NH);
  float sum = Wsb[h] + Whb[h];
#pragma unroll 8
  for (int i = 0; i < NH / 4; ++i) {
    float4 a = dr[i], w = wr[i];
    sum += a.x * w.x + a.y * w.y + a.z * w.z + a.w * w.w;
  }
  decb[b * NH + h] = sum;
}

// ---- main: enc-proj GEMM (bf16 MFMA) + bias + tanh + v-dot -> scores ----
// R11: ONE 1024-thread block (16 waves) = two R6 blocks fused. BM=128, BN=512,
// BK=32. Wave w: n-group wn=w&7, m-half wm=w>>3. Wave pairs (w, w+8) read the
// SAME packed-B chunks in the same barrier epoch -> 2nd read is an L1 hit,
// halving B-L2 traffic (the pipe co-equal with MFMA in the R6 ledger).
// Per-wave frame identical to R6 (acc 64 + bcur 16 + af 16 + slots 12 <= 128).
// A: f32 global loads 2-ahead (3-slot static rotation), cvt_pk->bf16 after the
// cluster, ds_write into 2x10KB double buffer. One s_barrier + lgkm(0)/step.
__global__ __launch_bounds__(1024, 4) void fused_main(const float* __restrict__ enc,
                                                      const unsigned short* __restrict__ Bp,
                                                      const float* __restrict__ decb,
                                                      const float* __restrict__ vw,
                                                      float* __restrict__ scores) {
  __shared__ __align__(16) char As[2][128 * APITCH];  // bf16 tiles, 2 x 10KB
  __shared__ float ssc[128];

  const int tid = threadIdx.x;
  const int lane = tid & 63;
  const int wave = tid >> 6;
  const int wn = wave & 7;    // n-group (pairs share B)
  const int wm = wave >> 3;   // m-half
  const int r15 = lane & 15;
  const int c4 = lane >> 4;
  const long long m0 = (long long)blockIdx.x * 128;

  if (tid < 128) ssc[tid] = 0.0f;

  // A staging: thread t -> row t>>3 (0..127), granule t&3? no: t&7 (4 f32 = 16B)
  const int arow = tid >> 3;
  const int agk = tid & 7;
  const float* aload = enc + (m0 + arow) * NE + agk * 4;
  const int awr = arow * APITCH + agk * 8;                 // bf16 bytes
  const int rdb = (wm * 64 + r15) * APITCH + c4 * 16;      // frag base (+ mi*16*APITCH)

  // packed B base for this wave's n-group (shared by wave and wave+8)
  const unsigned short* const bb = Bp + (long long)wn * 32 * 2048 + lane * 8;

  f32x4 acc[4][4];
#pragma unroll
  for (int mi = 0; mi < 4; ++mi)
#pragma unroll
    for (int ni = 0; ni < 4; ++ni) {
      f32x4 z = {0.f, 0.f, 0.f, 0.f};
      acc[mi][ni] = z;
    }

  // prologue: B(0)->bcur; A(0)->cvt->buf0; slots s1<-A(1), s2<-A(2)
  bf16x8 bcur[4];
#pragma unroll
  for (int ni = 0; ni < 4; ++ni) bcur[ni] = *(const bf16x8*)(bb + ni * 512);
  {
    float4 a0 = *(const float4*)(aload);
    unsigned int w0, w1;
    asm("v_cvt_pk_bf16_f32 %0, %1, %2" : "=v"(w0) : "v"(a0.x), "v"(a0.y));
    asm("v_cvt_pk_bf16_f32 %0, %1, %2" : "=v"(w1) : "v"(a0.z), "v"(a0.w));
    uint2 wv; wv.x = w0; wv.y = w1;
    *(uint2*)(&As[0][0] + awr) = wv;
  }
  float4 s0, s1, s2;  // slot(i%3) holds A(i)
  s1 = *(const float4*)(aload + 1 * 32);
  s2 = *(const float4*)(aload + 2 * 32);
  asm volatile("s_waitcnt lgkmcnt(0)" ::: "memory");
  __builtin_amdgcn_s_barrier();

#pragma unroll
  for (int t = 0; t < 32; ++t) {
    // ---- issue A(t+3) into slot((t+3)%3 == t%3) (free since step t-1) ----
    if (t < 29) {
      const float4* ap = (const float4*)(aload + (t + 3) * 32);
      if (t % 3 == 0)      s0 = *ap;
      else if (t % 3 == 1) s1 = *ap;
      else                 s2 = *ap;
    }
    // ---- A fragments from buf[t&1] (compiler emits counted lgkm) ----
    const char* Ab = &As[t & 1][0];
    bf16x8 af0 = *(const bf16x8*)(Ab + rdb);
    bf16x8 af1 = *(const bf16x8*)(Ab + 16 * APITCH + rdb);
    bf16x8 af2 = *(const bf16x8*)(Ab + 32 * APITCH + rdb);
    bf16x8 af3 = *(const bf16x8*)(Ab + 48 * APITCH + rdb);
    __builtin_amdgcn_s_setprio(1);
#pragma unroll
    for (int ni = 0; ni < 4; ++ni)
      acc[0][ni] = __builtin_amdgcn_mfma_f32_16x16x32_bf16(af0, bcur[ni], acc[0][ni], 0, 0, 0);
#pragma unroll
    for (int ni = 0; ni < 4; ++ni)
      acc[1][ni] = __builtin_amdgcn_mfma_f32_16x16x32_bf16(af1, bcur[ni], acc[1][ni], 0, 0, 0);
#pragma unroll
    for (int ni = 0; ni < 4; ++ni)
      acc[2][ni] = __builtin_amdgcn_mfma_f32_16x16x32_bf16(af2, bcur[ni], acc[2][ni], 0, 0, 0);
#pragma unroll
    for (int ni = 0; ni < 4; ++ni)
      acc[3][ni] = __builtin_amdgcn_mfma_f32_16x16x32_bf16(af3, bcur[ni], acc[3][ni], 0, 0, 0);
    __builtin_amdgcn_s_setprio(0);
    // ---- B(t+1) reload (WAR keeps it after the cluster; wave pair shares -> L1) ----
    if (t < 31) {
      const bf16x8* bp = (const bf16x8*)(bb + (t + 1) * 2048);
#pragma unroll
      for (int ni = 0; ni < 4; ++ni) bcur[ni] = bp[ni * 64];
    }
    // ---- cvt + write A(t+1) from slot((t+1)%3) into buf[(t+1)&1] ----
    if (t < 31) {
      float4 a;
      if (t % 3 == 0)      a = s1;   // (t+1)%3 == 1
      else if (t % 3 == 1) a = s2;   // (t+1)%3 == 2
      else                 a = s0;   // (t+1)%3 == 0
      unsigned int w0, w1;
      asm("v_cvt_pk_bf16_f32 %0, %1, %2" : "=v"(w0) : "v"(a.x), "v"(a.y));
      asm("v_cvt_pk_bf16_f32 %0, %1, %2" : "=v"(w1) : "v"(a.z), "v"(a.w));
      uint2 wv; wv.x = w0; wv.y = w1;
      *(uint2*)(&As[(t + 1) & 1][0] + awr) = wv;
    }
    asm volatile("s_waitcnt lgkmcnt(0)" ::: "memory");
    __builtin_amdgcn_sched_barrier(0);
    __builtin_amdgcn_s_barrier();
  }

  // epilogue: x = tanh(acc + dec[b,h]); score += v[h]*x
  // C/D layout: col = lane&15 (n), row = (lane>>4)*4 + j (m)
  const int bidx = (int)(m0 >> 12);
  const float* decrow = decb + bidx * NH;
  float part[4][4];
#pragma unroll
  for (int mi = 0; mi < 4; ++mi)
#pragma unroll
    for (int j = 0; j < 4; ++j) part[mi][j] = 0.f;

#pragma unroll
  for (int ni = 0; ni < 4; ++ni) {
    int col = (wn << 6) + ni * 16 + r15;
    float vc = vw[col];
    float dc = decrow[col];
#pragma unroll
    for (int mi = 0; mi < 4; ++mi)
#pragma unroll
      for (int j = 0; j < 4; ++j)
        part[mi][j] += vc * fast_tanh(acc[mi][ni][j] + dc);
  }
#pragma unroll
  for (int off = 1; off < 16; off <<= 1)
#pragma unroll
    for (int mi = 0; mi < 4; ++mi)
#pragma unroll
      for (int j = 0; j < 4; ++j)
        part[mi][j] += __shfl_xor(part[mi][j], off, 64);

  if (r15 == 0) {
#pragma unroll
    for (int mi = 0; mi < 4; ++mi)
#pragma unroll
      for (int j = 0; j < 4; ++j)
        atomicAdd(&ssc[wm * 64 + mi * 16 + c4 * 4 + j], part[mi][j]);
  }
  __syncthreads();
  if (tid < 128) scores[m0 + tid] = ssc[tid];
}

// ---- masked softmax over S per batch row ----
__global__ __launch_bounds__(1024) void softmax_kernel(const float* __restrict__ scores,
                                                       const int* __restrict__ mask,
                                                       float* __restrict__ out) {
  __shared__ float rmax[16];
  __shared__ float rsum[16];
  const int b = blockIdx.x;
  const int t = threadIdx.x;
  const int wid = t >> 6;
  const int ln = t & 63;
  const int base = b * NS;

  float s[4];
  int mk[4];
  float mx = -INFINITY;
#pragma unroll
  for (int i = 0; i < 4; ++i) {
    int idx = t + i * 1024;
    s[i] = scores[base + idx];
    mk[i] = mask[base + idx];
    if (mk[i]) mx = fmaxf(mx, s[i]);
  }
#pragma unroll
  for (int off = 1; off < 64; off <<= 1) mx = fmaxf(mx, __shfl_xor(mx, off, 64));
  if (ln == 0) rmax[wid] = mx;
  __syncthreads();
  float m2 = -INFINITY;
#pragma unroll
  for (int i = 0; i < 16; ++i) m2 = fmaxf(m2, rmax[i]);

  float e[4];
  float sum = 0.f;
#pragma unroll
  for (int i = 0; i < 4; ++i) {
    e[i] = mk[i] ? expf(s[i] - m2) : 0.f;
    sum += e[i];
  }
#pragma unroll
  for (int off = 1; off < 64; off <<= 1) sum += __shfl_xor(sum, off, 64);
  if (ln == 0) rsum[wid] = sum;
  __syncthreads();
  float tot = 0.f;
#pragma unroll
  for (int i = 0; i < 16; ++i) tot += rsum[i];
  float inv = 1.0f / tot;
#pragma unroll
  for (int i = 0; i < 4; ++i) {
    int idx = t + i * 1024;
    out[base + idx] = e[i] * inv;
  }
}

extern "C" void kernel_launch(void* const* d_in, const int* in_sizes, int n_in,
                              void* d_out, int out_size, void* d_ws, size_t ws_size,
                              hipStream_t stream) {
  const float* dec = (const float*)d_in[0];   // [64,512]
  const float* enc = (const float*)d_in[1];   // [64,4096,1024]
  const int* mask = (const int*)d_in[2];      // [64,4096]
  const float* Whw = (const float*)d_in[3];   // [512,1024]
  const float* Whb = (const float*)d_in[4];   // [512]
  const float* Wsw = (const float*)d_in[5];   // [512,512]
  const float* Wsb = (const float*)d_in[6];   // [512]
  const float* vw = (const float*)d_in[7];    // [1,512]
  float* out = (float*)d_out;                 // [64,4096]

  unsigned short* Bp = (unsigned short*)d_ws;                         // 1 MB packed W
  float* decb = (float*)((char*)d_ws + (1 << 20));                    // 128 KB
  float* scoresb = (float*)((char*)d_ws + (1 << 20) + (128 << 10));   // 1 MB

  prep_b_kernel<<<dim3(256), dim3(256), 0, stream>>>(Whw, Bp);
  prep_dec_kernel<<<dim3(64), dim3(512), 0, stream>>>(dec, Wsw, Wsb, Whb, decb);
  fused_main<<<dim3(2048), dim3(1024), 0, stream>>>(enc, Bp, decb, vw, scoresb);
  softmax_kernel<<<dim3(64), dim3(1024), 0, stream>>>(scoresb, mask, out);
}